// Round 16
// baseline (118.559 us; speedup 1.0000x reference)
//
#include <hip/hip_runtime.h>

// Involution2d, 2-kernel (R27: half-tile blocks for cross-phase overlap).
// Measured: inv plateau 46.4-46.8us across 3 apply variants (R15/R16/R25);
// Occupancy 69%, VALUBusy 27%, work-content floor ~15us -> un-hidden latency
// with 4 lockstep blocks/CU. Fix: 128-px blocks (256 thr), grid 2048 = 8
// blocks/CU, same 64-reg tier, kq 14,336B -> LDS fits all 8. Blocks drift
// across phases -> GEMM waves hide apply waves' latency and vice versa.
// K0 VERBATIM R13 (unpadded [b][oct][4096px][8ch]); totals-based cvt
// estimates proved unreliable (R2 vs R14 contradiction) -- judge by
// per-dispatch counters only.
// [R28: resubmit unchanged — R27 bench was a GPUAcquisitionTimeout, no data.]

#define B_   4
#define C_   256
#define G_   16
#define KK_  49
#define KS_  7
#define PD_  3

#define XP8_BYTES (B_*32*4096*8*2)       // 8,388,608
#define WBF_OFF   XP8_BYTES

typedef __attribute__((ext_vector_type(8))) short bf16x8;
typedef __attribute__((ext_vector_type(4))) float f32x4;
typedef unsigned short ushort_t;

__device__ inline unsigned f2bf(float f) {            // RNE fp32->bf16
    unsigned u = __float_as_uint(f);
    u += 0x7FFF + ((u >> 16) & 1);
    return u >> 16;
}

// ---------------- K0: x -> xp8 (channel-packed bf16); w -> bf16 ----------------
// VERBATIM the R13 kernel (directly measured 61.4-total round gave ~5us; keep).
__global__ __launch_bounds__(256)
void cvt_xp8(const float* __restrict__ x, const float* __restrict__ wk,
             ushort_t* __restrict__ xp8, unsigned* __restrict__ wbf) {
    const int t = threadIdx.x;
    if (blockIdx.x == 64) {   // W convert: 100352 f32 pairs, 16 slices
        const int slice = blockIdx.z * 4 + blockIdx.y;
        const float2* wk2 = (const float2*)wk;
        const int base = slice * 6272;
        for (int k = t; k < 6272; k += 256) {
            float2 v = wk2[base + k];
            wbf[base + k] = f2bf(v.x) | (f2bf(v.y) << 16);
        }
        return;
    }
    __shared__ float tile[64][65];
    const int p0 = blockIdx.x * 64;
    const int c0 = blockIdx.y * 64;       // 8 octs per slice
    const int b  = blockIdx.z;
    const int px_r = t & 63;
    #pragma unroll
    for (int i = 0; i < 16; ++i) {
        int ch = (t >> 6) + i * 4;
        tile[ch][px_r] = x[((size_t)(b * C_ + c0 + ch) << 12) + p0 + px_r];
    }
    __syncthreads();
    const int px = t & 63;
    const int ob = t >> 6;                // 0..3
    #pragma unroll
    for (int jj = 0; jj < 2; ++jj) {
        const int j = ob + jj * 4;        // oct within slice, 0..7
        unsigned u[4];
        #pragma unroll
        for (int k2 = 0; k2 < 4; ++k2) {
            float a0 = tile[j * 8 + 2 * k2][px];
            float a1 = tile[j * 8 + 2 * k2 + 1][px];
            u[k2] = f2bf(a0) | (f2bf(a1) << 16);
        }
        ushort_t* dst = xp8 + (((size_t)((b << 5) + (c0 >> 3) + j) << 12) + p0 + px) * 8;
        *(uint4*)dst = make_uint4(u[0], u[1], u[2], u[3]);
    }
}

// ---------------- K1: fused GEMM + apply (128-px blocks) ----------------
__global__ __launch_bounds__(256, 8)
void inv_fused(const ushort_t* __restrict__ xp8,
               const ushort_t* __restrict__ wbf,
               const float* __restrict__ bk,
               float* __restrict__ out) {
    __shared__ unsigned kq[7 * 128 * 4];      // 14,336 B  kq[q][pixel][4dw]

    const int bid = blockIdx.x;
    const int g   = bid >> 7;                 // 0..15
    const int b   = (bid >> 5) & 3;           // 0..3
    const int ht  = bid & 31;                 // half-tile: 2 image rows
    const int gy0 = ht * 2;
    const int p0  = ht * 128;

    const int tid  = threadIdx.x;
    const int wv   = tid >> 6;                // 0..3
    const int ln15 = tid & 15;
    const int quad = (tid & 63) >> 4;

    // ---- GEMM: wave wv owns n-cols p0+wv*32 (2 n-tiles) x 4 m-tiles ----
    f32x4 acc[8];
    #pragma unroll
    for (int i = 0; i < 8; ++i) acc[i] = (f32x4){0.f, 0.f, 0.f, 0.f};

    const char* bbase = (const char*)xp8 + ((size_t)b << 21);   // 32 octs * 64KB
    const char* abase = (const char*)wbf + (size_t)g * KK_ * 512;

    int vb0;
    {
        int gi0 = p0 + wv * 32 + ln15;             // nt=0 pixel index
        vb0 = ((quad << 12) + gi0) << 4;           // (quad*4096 + gi0)*16
    }
    int vb1 = vb0 + 256;                           // gi1 = gi0+16 -> +256B
    int va  = ln15 * 512 + quad * 16;              // mt 0..2: + mt*8192 via s-base
    const int va3 = 48 * 512 + quad * 16;          // mt 3: row clamped to 48

    #pragma unroll
    for (int k = 0; k < 8; ++k) {
        bf16x8 af0 = *(const bf16x8*)(abase + va);
        bf16x8 af1 = *(const bf16x8*)(abase + 8192 + va);
        bf16x8 af2 = *(const bf16x8*)(abase + 16384 + va);
        bf16x8 af3 = *(const bf16x8*)(abase + va3 + k * 64);
        bf16x8 bf0 = *(const bf16x8*)(bbase + vb0);
        bf16x8 bf1 = *(const bf16x8*)(bbase + vb1);
        acc[0] = __builtin_amdgcn_mfma_f32_16x16x32_bf16(af0, bf0, acc[0], 0, 0, 0);
        acc[1] = __builtin_amdgcn_mfma_f32_16x16x32_bf16(af0, bf1, acc[1], 0, 0, 0);
        acc[2] = __builtin_amdgcn_mfma_f32_16x16x32_bf16(af1, bf0, acc[2], 0, 0, 0);
        acc[3] = __builtin_amdgcn_mfma_f32_16x16x32_bf16(af1, bf1, acc[3], 0, 0, 0);
        acc[4] = __builtin_amdgcn_mfma_f32_16x16x32_bf16(af2, bf0, acc[4], 0, 0, 0);
        acc[5] = __builtin_amdgcn_mfma_f32_16x16x32_bf16(af2, bf1, acc[5], 0, 0, 0);
        acc[6] = __builtin_amdgcn_mfma_f32_16x16x32_bf16(af3, bf0, acc[6], 0, 0, 0);
        acc[7] = __builtin_amdgcn_mfma_f32_16x16x32_bf16(af3, bf1, acc[7], 0, 0, 0);
        va  += 64;                                 // +32 channels
        vb0 += 4 * 4096 * 16; vb1 += 4 * 4096 * 16;   // +4 octs
    }

    // ---- epilogue: acc -> kq[q7=mt*2+(quad>>1)][p], dword pair (quad&1)*2 ----
    #pragma unroll
    for (int mt = 0; mt < 3; ++mt) {                      // m <= 47
        const int m0 = mt * 16 + quad * 4;
        const float b0 = bk[g * KK_ + m0],     b1 = bk[g * KK_ + m0 + 1];
        const float b2 = bk[g * KK_ + m0 + 2], b3 = bk[g * KK_ + m0 + 3];
        const int q7 = mt * 2 + (quad >> 1);
        #pragma unroll
        for (int nt = 0; nt < 2; ++nt) {
            const int p = wv * 32 + nt * 16 + ln15;       // 0..127
            uint2 d;
            d.x = f2bf(acc[mt * 2 + nt][0] + b0) | (f2bf(acc[mt * 2 + nt][1] + b1) << 16);
            d.y = f2bf(acc[mt * 2 + nt][2] + b2) | (f2bf(acc[mt * 2 + nt][3] + b3) << 16);
            *(uint2*)&kq[(q7 * 128 + p) * 4 + (quad & 1) * 2] = d;
        }
    }
    if (quad == 0) {                                      // mt=3: only m=48 valid
        const float b48 = bk[g * KK_ + 48];
        #pragma unroll
        for (int nt = 0; nt < 2; ++nt) {
            const int p = wv * 32 + nt * 16 + ln15;
            kq[(6 * 128 + p) * 4] = f2bf(acc[6 + nt][0] + b48);   // lo=m48
        }
    }
    __syncthreads();   // the only barrier: kq complete

    // ---- my pixel's 49 kern values: 7x conflict-free ds_read_b128 ----
    const int pix = tid & 127;
    const int ho  = tid >> 7;
    unsigned kd[28];
    #pragma unroll
    for (int q = 0; q < 7; ++q) {
        uint4 h = *(const uint4*)&kq[(q * 128 + pix) * 4];
        kd[4*q] = h.x; kd[4*q+1] = h.y; kd[4*q+2] = h.z; kd[4*q+3] = h.w;
    }

    // ---- apply: taps direct from unpadded xp8, clamped addr + kk-masking ----
    const int py = pix >> 6, pxx = pix & 63;
    const char* obse = (const char*)xp8 + ((size_t)((b << 5) + 2 * g + ho) << 16);

    float a[8];
    #pragma unroll
    for (int q = 0; q < 8; ++q) a[q] = 0.f;
    #pragma unroll
    for (int kh = 0; kh < KS_; ++kh) {
        const int sy  = gy0 + py + kh - PD_;
        const int csy = min(max(sy, 0), 63);
        const bool oky = (sy == csy);
        const char* hrow = obse + ((size_t)csy << 10);    // 64 cells * 16B
        #pragma unroll
        for (int kw = 0; kw < KS_; ++kw) {
            const int sx  = pxx + kw - PD_;
            const int csx = min(max(sx, 0), 63);
            uint4 hv = *(const uint4*)(hrow + (csx << 4));
            const int t49 = kh * KS_ + kw;
            unsigned d = kd[t49 >> 1];
            float kk = __uint_as_float((t49 & 1) ? (d & 0xffff0000u) : (d << 16));
            kk = (oky && sx == csx) ? kk : 0.f;           // zero OOB taps
            a[0] = fmaf(__uint_as_float(hv.x << 16), kk, a[0]);
            a[1] = fmaf(__uint_as_float(hv.x),       kk, a[1]);
            a[2] = fmaf(__uint_as_float(hv.y << 16), kk, a[2]);
            a[3] = fmaf(__uint_as_float(hv.y),       kk, a[3]);
            a[4] = fmaf(__uint_as_float(hv.z << 16), kk, a[4]);
            a[5] = fmaf(__uint_as_float(hv.z),       kk, a[5]);
            a[6] = fmaf(__uint_as_float(hv.w << 16), kk, a[6]);
            a[7] = fmaf(__uint_as_float(hv.w),       kk, a[7]);
        }
    }
    const size_t o = ((size_t)(b * C_ + g * 16 + ho * 8) << 12) + p0 + pix;
    #pragma unroll
    for (int q = 0; q < 8; ++q)
        out[o + ((size_t)q << 12)] = a[q];
}

extern "C" void kernel_launch(void* const* d_in, const int* in_sizes, int n_in,
                              void* d_out, int out_size, void* d_ws, size_t ws_size,
                              hipStream_t stream) {
    const float* x  = (const float*)d_in[0];
    const float* wk = (const float*)d_in[1];
    const float* bk = (const float*)d_in[2];
    float* o = (float*)d_out;

    ushort_t* xp8 = (ushort_t*)d_ws;
    unsigned* wbf = (unsigned*)((char*)d_ws + WBF_OFF);

    cvt_xp8<<<dim3(65, 4, B_), dim3(256), 0, stream>>>(x, wk, xp8, wbf);
    inv_fused<<<dim3(2048), dim3(256), 0, stream>>>(
        xp8, (const ushort_t*)wbf, bk, o);
}

// Round 17
// 106.324 us; speedup vs baseline: 1.1151x; 1.1151x over previous
//
#include <hip/hip_runtime.h>

// Involution2d, 2-kernel (R29: fragment-linear W layout -> coalesced A-loads).
// Plateau diagnosis: inv stuck 46-48us across 4 structurally different apply
// variants; Occ 69%, VALUBusy 27%, Mfma 6.7% all invariant -> VMEM-issue (TA)
// bound. The shared culprit: A-frag loads scatter 16 cache lines/wave
// (ln15*512B stride). Fix: K0 stores W in MFMA-fragment-linear order
// wbf[g][mt][k][lane][16B] (row-48 clamp pre-baked) -> every A-load is one
// contiguous 1KB coalesced wave load. Lane->element mapping preserved exactly.
// K1 otherwise VERBATIM R25 (best measured: 46.4-46.6us, 64-reg tier,
// LB(512,8), kq[7][256] transposed LDS, masked global taps).
// K0 x-conversion VERBATIM R13. Bank-conflict counter is capped at 2^18 --
// ignore it. Judge by per-dispatch dur + VALUBusy + FETCH only.

#define B_   4
#define C_   256
#define G_   16
#define KK_  49
#define KS_  7
#define PD_  3

#define XP8_BYTES (B_*32*4096*8*2)       // 8,388,608
#define WBF_OFF   XP8_BYTES
// wbf fragment-linear: 16g * 4mt * 8k * 64lane * 16B = 524,288 B

typedef __attribute__((ext_vector_type(8))) short bf16x8;
typedef __attribute__((ext_vector_type(4))) float f32x4;
typedef unsigned short ushort_t;

__device__ inline unsigned f2bf(float f) {            // RNE fp32->bf16
    unsigned u = __float_as_uint(f);
    u += 0x7FFF + ((u >> 16) & 1);
    return u >> 16;
}

// ---------------- K0: x -> xp8 (channel-packed bf16); w -> fragment-linear bf16 ----------------
__global__ __launch_bounds__(256)
void cvt_xp8(const float* __restrict__ x, const float* __restrict__ wk,
             ushort_t* __restrict__ xp8, unsigned* __restrict__ wbf) {
    const int t = threadIdx.x;
    if (blockIdx.x == 64) {   // W -> fragment-linear: one g per (y,z) block
        const int g = blockIdx.z * 4 + blockIdx.y;
        for (int p = t; p < 2048; p += 256) {     // 4mt * 8k * 64lane
            const int lane = p & 63;
            const int k    = (p >> 6) & 7;
            const int mt   = p >> 9;
            const int r    = min(mt * 16 + (lane & 15), KK_ - 1);  // row clamp
            const int ch   = k * 32 + (lane >> 4) * 8;
            const float* src = wk + (size_t)(g * KK_ + r) * C_ + ch;
            unsigned u[4];
            #pragma unroll
            for (int j = 0; j < 4; ++j)
                u[j] = f2bf(src[2 * j]) | (f2bf(src[2 * j + 1]) << 16);
            *(uint4*)((char*)wbf + (((size_t)(g * 4 + mt) * 8 + k) * 64 + lane) * 16)
                = make_uint4(u[0], u[1], u[2], u[3]);
        }
        return;
    }
    __shared__ float tile[64][65];
    const int p0 = blockIdx.x * 64;
    const int c0 = blockIdx.y * 64;       // 8 octs per slice
    const int b  = blockIdx.z;
    const int px_r = t & 63;
    #pragma unroll
    for (int i = 0; i < 16; ++i) {
        int ch = (t >> 6) + i * 4;
        tile[ch][px_r] = x[((size_t)(b * C_ + c0 + ch) << 12) + p0 + px_r];
    }
    __syncthreads();
    const int px = t & 63;
    const int ob = t >> 6;                // 0..3
    #pragma unroll
    for (int jj = 0; jj < 2; ++jj) {
        const int j = ob + jj * 4;        // oct within slice, 0..7
        unsigned u[4];
        #pragma unroll
        for (int k2 = 0; k2 < 4; ++k2) {
            float a0 = tile[j * 8 + 2 * k2][px];
            float a1 = tile[j * 8 + 2 * k2 + 1][px];
            u[k2] = f2bf(a0) | (f2bf(a1) << 16);
        }
        ushort_t* dst = xp8 + (((size_t)((b << 5) + (c0 >> 3) + j) << 12) + p0 + px) * 8;
        *(uint4*)dst = make_uint4(u[0], u[1], u[2], u[3]);
    }
}

// ---------------- K1: fused GEMM + apply (coalesced A, masked taps) ----------------
__global__ __launch_bounds__(512, 8)
void inv_fused(const ushort_t* __restrict__ xp8,
               const ushort_t* __restrict__ wbf,
               const float* __restrict__ bk,
               float* __restrict__ out) {
    __shared__ unsigned kq[7 * 256 * 4];      // 28,672 B  kq[q][pixel][4dw]

    const int bid  = blockIdx.x;
    const int g    = bid >> 6;
    const int b    = (bid >> 4) & 3;
    const int tile = bid & 15;
    const int gy0  = tile * 4;
    const int p0   = tile * 256;

    const int tid  = threadIdx.x;
    const int wv   = tid >> 6;                // 0..7
    const int ln15 = tid & 15;
    const int quad = (tid & 63) >> 4;

    // ---- GEMM: wave wv owns n-cols p0+wv*32 (2 n-tiles) x 4 m-tiles ----
    f32x4 acc[8];
    #pragma unroll
    for (int i = 0; i < 8; ++i) acc[i] = (f32x4){0.f, 0.f, 0.f, 0.f};

    const char* bbase = (const char*)xp8 + ((size_t)b << 21);   // 32 octs * 64KB
    const char* abase = (const char*)wbf + ((size_t)g << 15);   // g * 32768

    int vb0;
    {
        int gi0 = p0 + wv * 32 + ln15;             // nt=0 pixel index
        vb0 = ((quad << 12) + gi0) << 4;           // (quad*4096 + gi0)*16
    }
    int vb1 = vb0 + 256;                           // gi1 = gi0+16 -> +256B
    const int aoff = (tid & 63) * 16;              // lane*16, coalesced

    #pragma unroll
    for (int k = 0; k < 8; ++k) {
        bf16x8 af0 = *(const bf16x8*)(abase + k * 1024 + aoff);
        bf16x8 af1 = *(const bf16x8*)(abase + 8192  + k * 1024 + aoff);
        bf16x8 af2 = *(const bf16x8*)(abase + 16384 + k * 1024 + aoff);
        bf16x8 af3 = *(const bf16x8*)(abase + 24576 + k * 1024 + aoff);
        bf16x8 bf0 = *(const bf16x8*)(bbase + vb0);
        bf16x8 bf1 = *(const bf16x8*)(bbase + vb1);
        acc[0] = __builtin_amdgcn_mfma_f32_16x16x32_bf16(af0, bf0, acc[0], 0, 0, 0);
        acc[1] = __builtin_amdgcn_mfma_f32_16x16x32_bf16(af0, bf1, acc[1], 0, 0, 0);
        acc[2] = __builtin_amdgcn_mfma_f32_16x16x32_bf16(af1, bf0, acc[2], 0, 0, 0);
        acc[3] = __builtin_amdgcn_mfma_f32_16x16x32_bf16(af1, bf1, acc[3], 0, 0, 0);
        acc[4] = __builtin_amdgcn_mfma_f32_16x16x32_bf16(af2, bf0, acc[4], 0, 0, 0);
        acc[5] = __builtin_amdgcn_mfma_f32_16x16x32_bf16(af2, bf1, acc[5], 0, 0, 0);
        acc[6] = __builtin_amdgcn_mfma_f32_16x16x32_bf16(af3, bf0, acc[6], 0, 0, 0);
        acc[7] = __builtin_amdgcn_mfma_f32_16x16x32_bf16(af3, bf1, acc[7], 0, 0, 0);
        vb0 += 4 * 4096 * 16; vb1 += 4 * 4096 * 16;   // +4 octs
    }

    // ---- epilogue: acc -> kq[q7=mt*2+(quad>>1)][p], dword pair (quad&1)*2 ----
    #pragma unroll
    for (int mt = 0; mt < 3; ++mt) {                      // m <= 47
        const int m0 = mt * 16 + quad * 4;
        const float b0 = bk[g * KK_ + m0],     b1 = bk[g * KK_ + m0 + 1];
        const float b2 = bk[g * KK_ + m0 + 2], b3 = bk[g * KK_ + m0 + 3];
        const int q7 = mt * 2 + (quad >> 1);
        #pragma unroll
        for (int nt = 0; nt < 2; ++nt) {
            const int p = wv * 32 + nt * 16 + ln15;
            uint2 d;
            d.x = f2bf(acc[mt * 2 + nt][0] + b0) | (f2bf(acc[mt * 2 + nt][1] + b1) << 16);
            d.y = f2bf(acc[mt * 2 + nt][2] + b2) | (f2bf(acc[mt * 2 + nt][3] + b3) << 16);
            *(uint2*)&kq[(q7 * 256 + p) * 4 + (quad & 1) * 2] = d;
        }
    }
    if (quad == 0) {                                      // mt=3: only m=48 valid
        const float b48 = bk[g * KK_ + 48];
        #pragma unroll
        for (int nt = 0; nt < 2; ++nt) {
            const int p = wv * 32 + nt * 16 + ln15;
            kq[(6 * 256 + p) * 4] = f2bf(acc[6 + nt][0] + b48);   // lo=m48
        }
    }
    __syncthreads();   // the only barrier: kq complete

    // ---- my pixel's 49 kern values: 7x ds_read_b128 ----
    const int pix = tid & 255;
    const int ho  = tid >> 8;
    unsigned kd[28];
    #pragma unroll
    for (int q = 0; q < 7; ++q) {
        uint4 h = *(const uint4*)&kq[(q * 256 + pix) * 4];
        kd[4*q] = h.x; kd[4*q+1] = h.y; kd[4*q+2] = h.z; kd[4*q+3] = h.w;
    }

    // ---- apply: taps direct from unpadded xp8, clamped addr + kk-masking ----
    const int py = pix >> 6, pxx = pix & 63;
    const char* obse = (const char*)xp8 + ((size_t)((b << 5) + 2 * g + ho) << 16);

    float a[8];
    #pragma unroll
    for (int q = 0; q < 8; ++q) a[q] = 0.f;
    #pragma unroll
    for (int kh = 0; kh < KS_; ++kh) {
        const int sy  = gy0 + py + kh - PD_;
        const int csy = min(max(sy, 0), 63);
        const bool oky = (sy == csy);
        const char* hrow = obse + ((size_t)csy << 10);    // 64 cells * 16B
        #pragma unroll
        for (int kw = 0; kw < KS_; ++kw) {
            const int sx  = pxx + kw - PD_;
            const int csx = min(max(sx, 0), 63);
            uint4 hv = *(const uint4*)(hrow + (csx << 4));
            const int t49 = kh * KS_ + kw;
            unsigned d = kd[t49 >> 1];
            float kk = __uint_as_float((t49 & 1) ? (d & 0xffff0000u) : (d << 16));
            kk = (oky && sx == csx) ? kk : 0.f;           // zero OOB taps
            a[0] = fmaf(__uint_as_float(hv.x << 16), kk, a[0]);
            a[1] = fmaf(__uint_as_float(hv.x),       kk, a[1]);
            a[2] = fmaf(__uint_as_float(hv.y << 16), kk, a[2]);
            a[3] = fmaf(__uint_as_float(hv.y),       kk, a[3]);
            a[4] = fmaf(__uint_as_float(hv.z << 16), kk, a[4]);
            a[5] = fmaf(__uint_as_float(hv.z),       kk, a[5]);
            a[6] = fmaf(__uint_as_float(hv.w << 16), kk, a[6]);
            a[7] = fmaf(__uint_as_float(hv.w),       kk, a[7]);
        }
    }
    const size_t o = ((size_t)(b * C_ + g * 16 + ho * 8) << 12) + p0 + pix;
    #pragma unroll
    for (int q = 0; q < 8; ++q)
        out[o + ((size_t)q << 12)] = a[q];
}

extern "C" void kernel_launch(void* const* d_in, const int* in_sizes, int n_in,
                              void* d_out, int out_size, void* d_ws, size_t ws_size,
                              hipStream_t stream) {
    const float* x  = (const float*)d_in[0];
    const float* wk = (const float*)d_in[1];
    const float* bk = (const float*)d_in[2];
    float* o = (float*)d_out;

    ushort_t* xp8 = (ushort_t*)d_ws;
    unsigned* wbf = (unsigned*)((char*)d_ws + WBF_OFF);

    cvt_xp8<<<dim3(65, 4, B_), dim3(256), 0, stream>>>(x, wk, xp8, wbf);
    inv_fused<<<dim3(1024), dim3(512), 0, stream>>>(
        xp8, (const ushort_t*)wbf, bk, o);
}